// Round 10
// baseline (188.480 us; speedup 1.0000x reference)
//
#include <hip/hip_runtime.h>
#include <hip/hip_bf16.h>

typedef __attribute__((ext_vector_type(8))) short short8;
typedef __attribute__((ext_vector_type(4))) float f32x4;

static constexpr int Cdim = 2048;
static constexpr int NFRM = 512;        // B*T
static constexpr int Pdim = 16;
static constexpr int MROWS = NFRM * Pdim;   // 8192
static constexpr float EPS = 1e-5f;

// round-to-nearest-even fp32 -> bf16 bits
__device__ __forceinline__ unsigned short f2b(float x) {
  union { float f; unsigned u; } v; v.f = x;
  unsigned r = v.u + 0x7fffu + ((v.u >> 16) & 1u);
  return (unsigned short)(r >> 16);
}

__device__ __forceinline__ void gload16(const void* g, void* l) {
  __builtin_amdgcn_global_load_lds(
      (const __attribute__((address_space(1))) unsigned int*)g,
      (__attribute__((address_space(3))) unsigned int*)l, 16, 0, 0);
}

// ---------------- small prep kernels ----------------

__global__ __launch_bounds__(256) void cast3_kernel(
    const float* __restrict__ s0, const float* __restrict__ s1, const float* __restrict__ s2,
    unsigned short* __restrict__ d0, unsigned short* __restrict__ d1, unsigned short* __restrict__ d2)
{
  long i = (long)blockIdx.x * 256 + threadIdx.x;
  const float* s; unsigned short* d; long off;
  if (i < 1048576)      { s = s0; d = d0; off = i; }
  else if (i < 2097152) { s = s1; d = d1; off = i - 1048576; }
  else                  { s = s2; d = d2; off = i - 2097152; }
  float4 v = reinterpret_cast<const float4*>(s)[off];
  union { unsigned short u[4]; unsigned long long q; } o;
  o.u[0] = f2b(v.x); o.u[1] = f2b(v.y); o.u[2] = f2b(v.z); o.u[3] = f2b(v.w);
  *reinterpret_cast<unsigned long long*>(d + off * 4) = o.q;
}

__global__ __launch_bounds__(256) void mean_cast_kernel(
    const float* __restrict__ X, unsigned short* __restrict__ Mb)
{
  int idx = blockIdx.x * 256 + threadIdx.x;
  int n  = idx >> 9;
  int c4 = idx & 511;
  const float4* xp = reinterpret_cast<const float4*>(X) + (long)n * (Pdim * 512) + c4;
  float4 s = {0.f, 0.f, 0.f, 0.f};
  #pragma unroll
  for (int p = 0; p < Pdim; ++p) {
    float4 v = xp[(long)p * 512];
    s.x += v.x; s.y += v.y; s.z += v.z; s.w += v.w;
  }
  const float r = 1.f / 16.f;
  union { unsigned short u[4]; unsigned long long q; } o;
  o.u[0] = f2b(s.x * r); o.u[1] = f2b(s.y * r); o.u[2] = f2b(s.z * r); o.u[3] = f2b(s.w * r);
  *reinterpret_cast<unsigned long long*>(Mb + (long)idx * 4) = o.q;
}

// attn partials (4-way split-K) -> sigmoid gate: a = sigmoid(sum P + b_att); Xg = bf16(X*a)
__global__ __launch_bounds__(256) void gate_kernel(
    const float* __restrict__ X, const float* __restrict__ PA, const float* __restrict__ PB,
    const float* __restrict__ b_att, unsigned short* __restrict__ Xg)
{
  constexpr long F = 512L * 2048;
  long idx = (long)blockIdx.x * 256 + threadIdx.x;
  int c4 = (int)(idx & 511);
  long np = idx >> 9;
  long n  = np >> 4;
  float4 x  = reinterpret_cast<const float4*>(X)[idx];
  float4 p0 = reinterpret_cast<const float4*>(PA)[n * 512 + c4];
  float4 p1 = reinterpret_cast<const float4*>(PA + F)[n * 512 + c4];
  float4 p2 = reinterpret_cast<const float4*>(PB)[n * 512 + c4];
  float4 p3 = reinterpret_cast<const float4*>(PB + F)[n * 512 + c4];
  float4 bb = reinterpret_cast<const float4*>(b_att)[c4];
  float4 a;
  a.x = 1.f / (1.f + __expf(-(p0.x + p1.x + p2.x + p3.x + bb.x)));
  a.y = 1.f / (1.f + __expf(-(p0.y + p1.y + p2.y + p3.y + bb.y)));
  a.z = 1.f / (1.f + __expf(-(p0.z + p1.z + p2.z + p3.z + bb.z)));
  a.w = 1.f / (1.f + __expf(-(p0.w + p1.w + p2.w + p3.w + bb.w)));
  union { unsigned short u[4]; unsigned long long q; } o;
  o.u[0] = f2b(x.x * a.x); o.u[1] = f2b(x.y * a.y);
  o.u[2] = f2b(x.z * a.z); o.u[3] = f2b(x.w * a.w);
  *reinterpret_cast<unsigned long long*>(Xg + idx * 4) = o.q;
}

// ---------------- small attn GEMM, split-K=4, raw partial outputs ----------------
__global__ __launch_bounds__(256) void gemm_att_sk(
    const unsigned short* __restrict__ A,
    const unsigned short* __restrict__ B,
    float* __restrict__ PA, float* __restrict__ PB)
{
  constexpr int N = 2048, K = 2048, KH = 512;
  constexpr long F = 512L * 2048;
  __shared__ unsigned short As[128 * 32];
  __shared__ unsigned short Bs[128 * 32];
  const int t = threadIdx.x;
  const int lane = t & 63;
  const int wid = t >> 6;
  const int wr = wid >> 1, wc = wid & 1;
  const int m0 = blockIdx.x * 128, n0 = blockIdx.y * 128;
  const int k0 = blockIdx.z * KH;
  float* out = (blockIdx.z < 2) ? (PA + (long)blockIdx.z * F) : (PB + (long)(blockIdx.z - 2) * F);

  f32x4 acc[4][4];
  #pragma unroll
  for (int i = 0; i < 4; i++)
    #pragma unroll
    for (int j = 0; j < 4; j++) acc[i][j] = (f32x4){0.f, 0.f, 0.f, 0.f};

  const int srow = t >> 2;
  const int scol = (t & 3) * 8;
  const long aoff0 = (long)(m0 + srow) * K + scol;
  const long aoff1 = (long)(m0 + 64 + srow) * K + scol;
  const long boff0 = (long)(n0 + srow) * K + scol;
  const long boff1 = (long)(n0 + 64 + srow) * K + scol;
  char* AsB = (char*)As;
  char* BsB = (char*)Bs;

  const int fr = lane & 15;
  const int fk = (lane >> 4) * 8;

  for (int kt = k0; kt < k0 + KH; kt += 32) {
    __syncthreads();
    gload16(A + aoff0 + kt, AsB + t * 16);
    gload16(A + aoff1 + kt, AsB + 4096 + t * 16);
    gload16(B + boff0 + kt, BsB + t * 16);
    gload16(B + boff1 + kt, BsB + 4096 + t * 16);
    __syncthreads();
    short8 af[4], bfr[4];
    #pragma unroll
    for (int m = 0; m < 4; m++)
      af[m] = *reinterpret_cast<const short8*>(&As[(wr * 64 + m * 16 + fr) * 32 + fk]);
    #pragma unroll
    for (int n = 0; n < 4; n++)
      bfr[n] = *reinterpret_cast<const short8*>(&Bs[(wc * 64 + n * 16 + fr) * 32 + fk]);
    #pragma unroll
    for (int m = 0; m < 4; m++)
      #pragma unroll
      for (int n = 0; n < 4; n++)
        acc[m][n] = __builtin_amdgcn_mfma_f32_16x16x32_bf16(af[m], bfr[n], acc[m][n], 0, 0, 0);
  }

  const int l4 = lane >> 4;
  #pragma unroll
  for (int m = 0; m < 4; m++) {
    const int r0 = m0 + wr * 64 + m * 16 + l4 * 4;
    #pragma unroll
    for (int n = 0; n < 4; n++) {
      const int cn = n0 + wc * 64 + n * 16 + fr;
      #pragma unroll
      for (int j = 0; j < 4; j++)
        out[(long)(r0 + j) * N + cn] = acc[m][n][j];
    }
  }
}

// --- 256^2 GEMM, 16x16x32, 4-REGION schedule (pure-MFMA regions R2/R4) ---
// C[M,N] = A[M,K] @ B[N,K]^T, bf16 in / fp32 acc.
//   EPI=1: Cb = bf16(relu(BN_P16(acc)*gamma+beta))
//   EPI=2: Cf = acc + bias
// Evidence (R4..R9): per-iter LDS 4608cyc + MFMA 4967cyc ~= measured 9790 ->
// pipes fully SERIAL under the 8-phase structure. Fix: 4 regions of 32 MFMA,
// mh-major: R1=mh0xE R2=mh1xE R3=mh0xO R4=mh1xO. All E reads in R1 (16 front
// + 8 per-group embeds of af-mh1); R2/R4 are PURE MFMA (operands in regs) ->
// reads hide under 1242-cyc windows. Sync: 4 bars + 2 vmcnt + 1 lgkm/iter.
// Ledger: VMC(4)@R1-pre confirms {A(e),B(e)} (leaves B(o));
//         VMC(4)@R3-pre confirms {B(o),A(o)} (leaves A(e+2)).
// Stages post-bar: R1:A(o) R2:A(e+2) R3:B(e+2) R4:B(o+2).
// WAR: LGK0 tail at R1-end pins af-mh1 embeds before bar2's A(e+2) overwrite;
// all other overwrites >=1 consuming-MFMA-pinned barrier after last read.
template<int EPI>
__global__ __launch_bounds__(512, 2) void gemm256(
    const unsigned short* __restrict__ A,
    const unsigned short* __restrict__ Bp,
    int Kk, int Nn, int nbx,
    const float* __restrict__ bias,
    const float* __restrict__ gamma,
    const float* __restrict__ beta,
    float* __restrict__ Cf,
    unsigned short* __restrict__ Cb)
{
  __shared__ char lds[131072];
  const int t = threadIdx.x;
  const int lane = t & 63;
  const int wid = t >> 6;
  const int wr = wid >> 2;        // 0..1  (M-half)
  const int wc = wid & 3;         // 0..3  (N-quarter)

  // T1: bijective XCD swizzle (gridDim.x % 8 == 0 by construction)
  const int nw = gridDim.x;
  const int wg = (blockIdx.x & 7) * (nw >> 3) + (blockIdx.x >> 3);
  const int bx = wg % nbx;
  const int by = wg / nbx;
  const int m0 = bx << 8, n0 = by << 8;

  const int NT = Kk >> 6;         // K-tiles (BK=64), even, >=4
  const int NI = NT >> 1;         // unroll-2 iterations

  const long h64 = (long)64 * Kk, h128 = (long)128 * Kk;
  const int row0 = t >> 3;
  const int col0 = ((t & 7) * 8) ^ ((row0 & 7) << 3);   // pre-swizzled source col (elems)
  const unsigned short* gA = A  + (long)(m0 + row0) * Kk + col0;
  const unsigned short* gB = Bp + (long)(n0 + row0) * Kk + col0;

  const int fr_ = lane & 15;
  const int cb0 = ((lane >> 4) << 4) ^ ((fr_ & 7) << 4); // swizzled read col (bytes)
  const int aB = (wr << 14) + fr_ * 128;
  const int bB = 32768 + ((wc >> 1) << 14) + ((wc & 1) << 13) + fr_ * 128;

#define STG(gp_, ko_, lo_) do { \
    const unsigned short* g0_ = (gp_) + (ko_); \
    gload16(g0_, lds + (lo_) + (t << 4)); \
    gload16(g0_ + h64, lds + (lo_) + 8192 + (t << 4)); } while (0)

#define LDSA(buf_, m_, ks_) (*(const short8*)(lds + (buf_) * 65536 + aB + (m_) * 2048 + (cb0 ^ ((ks_) << 6))))
#define LDSB(buf_, n_, ks_) (*(const short8*)(lds + (buf_) * 65536 + bB + (n_) * 2048 + (cb0 ^ ((ks_) << 6))))

// 16 front reads, first-needed first (af[0], bf0[0] lead)
#define REGION_RD(buf_) do { \
    af[0][0] = LDSA(buf_, 0, 0); af[0][1] = LDSA(buf_, 0, 1); \
    bf0[0][0] = LDSB(buf_, 0, 0); bf0[0][1] = LDSB(buf_, 0, 1); \
    af[1][0] = LDSA(buf_, 1, 0); af[1][1] = LDSA(buf_, 1, 1); \
    bf0[1][0] = LDSB(buf_, 1, 0); bf0[1][1] = LDSB(buf_, 1, 1); \
    af[2][0] = LDSA(buf_, 2, 0); af[2][1] = LDSA(buf_, 2, 1); \
    b23[0][0] = LDSB(buf_, 2, 0); b23[0][1] = LDSB(buf_, 2, 1); \
    af[3][0] = LDSA(buf_, 3, 0); af[3][1] = LDSA(buf_, 3, 1); \
    b23[1][0] = LDSB(buf_, 3, 0); b23[1][1] = LDSB(buf_, 3, 1); } while (0)

#define MF(a_, b_, c_) __builtin_amdgcn_mfma_f32_16x16x32_bf16(a_, b_, c_, 0, 0, 0)

// 32 MFMA (one mh x all n); EMB_: per-group re-read af[mi] <- (buf_, 4+mi)
#define MHALF(buf_, base_, EMB_) do { \
    _Pragma("unroll") \
    for (int mi = 0; mi < 4; ++mi) { \
      acc[(base_) + mi][0] = MF(af[mi][0], bf0[0][0], acc[(base_) + mi][0]); \
      acc[(base_) + mi][0] = MF(af[mi][1], bf0[0][1], acc[(base_) + mi][0]); \
      acc[(base_) + mi][1] = MF(af[mi][0], bf0[1][0], acc[(base_) + mi][1]); \
      acc[(base_) + mi][1] = MF(af[mi][1], bf0[1][1], acc[(base_) + mi][1]); \
      acc[(base_) + mi][2] = MF(af[mi][0], b23[0][0], acc[(base_) + mi][2]); \
      acc[(base_) + mi][2] = MF(af[mi][1], b23[0][1], acc[(base_) + mi][2]); \
      acc[(base_) + mi][3] = MF(af[mi][0], b23[1][0], acc[(base_) + mi][3]); \
      acc[(base_) + mi][3] = MF(af[mi][1], b23[1][1], acc[(base_) + mi][3]); \
      if (EMB_) { af[mi][0] = LDSA(buf_, 4 + mi, 0); af[mi][1] = LDSA(buf_, 4 + mi, 1); } \
    } } while (0)

#define BARX() do { \
    __builtin_amdgcn_sched_barrier(0); \
    __builtin_amdgcn_s_barrier(); \
    __builtin_amdgcn_sched_barrier(0); } while (0)

#define LGK0() do { \
    asm volatile("s_waitcnt lgkmcnt(0)" ::: "memory"); \
    __builtin_amdgcn_sched_barrier(0); } while (0)

#define PRIO1() __builtin_amdgcn_s_setprio(1)
#define PRIO0() __builtin_amdgcn_s_setprio(0)
#define VMC(n_) asm volatile("s_waitcnt vmcnt(" #n_ ")" ::: "memory")

  f32x4 acc[8][4];
  #pragma unroll
  for (int i = 0; i < 8; i++)
    #pragma unroll
    for (int j = 0; j < 4; j++) acc[i][j] = (f32x4){0.f, 0.f, 0.f, 0.f};

  short8 af[4][2], bf0[2][2], b23[2][2];

  // prologue: bare stages; the loop's R1-pre VMC(4)+bar is the confirm.
  STG(gA, 0, 0);                    // A(e0)
  STG(gA + h128, 0, 16384);
  STG(gB, 0, 32768);                // B(e0)
  STG(gB + h128, 0, 49152);
  STG(gB, 64, 98304);               // B(o0)
  STG(gB + h128, 64, 114688);

#define ITERBODY(LAST_) do { \
    /* R1: mh0 x E; confirm {A(e),B(e)}; stage A(o); 16 front + 8 embed reads */ \
    VMC(4); \
    BARX(); \
    STG(gA, ko + 64, 65536); \
    STG(gA + h128, ko + 64, 81920); \
    REGION_RD(0); \
    PRIO1(); MHALF(0, 0, 1); PRIO0(); \
    LGK0(); \
    /* R2: mh1 x E; pure MFMA; stage A(e+2) */ \
    BARX(); \
    if (!(LAST_)) { STG(gA, ko + 128, 0); STG(gA + h128, ko + 128, 16384); } \
    PRIO1(); MHALF(0, 4, 0); PRIO0(); \
    /* R3: mh0 x O; confirm {B(o),A(o)}; stage B(e+2); 16 front + 8 embed */ \
    if (LAST_) { VMC(0); } else { VMC(4); } \
    BARX(); \
    if (!(LAST_)) { STG(gB, ko + 128, 32768); STG(gB + h128, ko + 128, 49152); } \
    REGION_RD(1); \
    PRIO1(); MHALF(1, 0, 1); PRIO0(); \
    /* R4: mh1 x O; pure MFMA; stage B(o+2) */ \
    BARX(); \
    if (!(LAST_)) { STG(gB, ko + 192, 98304); STG(gB + h128, ko + 192, 114688); } \
    PRIO1(); MHALF(1, 4, 0); PRIO0(); \
  } while (0)

  long ko = 0;
  for (int i = 0; i < NI - 1; ++i, ko += 128) {
    ITERBODY(0);
  }
  ITERBODY(1);

  // ---- epilogue (acc only; no LDS use, no barrier needed)
  const int l4 = lane >> 4;
  #pragma unroll
  for (int m = 0; m < 8; ++m) {
    const int r0 = m0 + wr * 128 + m * 16 + l4 * 4;
    #pragma unroll
    for (int n = 0; n < 4; ++n) {
      const int cn = n0 + wc * 64 + n * 16 + fr_;
      if constexpr (EPI == 1) {
        float s1 = 0.f, s2 = 0.f;
        #pragma unroll
        for (int j = 0; j < 4; j++) { float v = acc[m][n][j]; s1 += v; s2 += v * v; }
        s1 += __shfl_xor(s1, 16); s2 += __shfl_xor(s2, 16);
        s1 += __shfl_xor(s1, 32); s2 += __shfl_xor(s2, 32);
        const float mean = s1 * 0.0625f;
        const float var  = s2 * 0.0625f - mean * mean;
        const float sc = rsqrtf(var + EPS) * gamma[cn];
        const float sh = beta[cn] - mean * sc;
        #pragma unroll
        for (int j = 0; j < 4; j++) {
          float v = fmaxf(acc[m][n][j] * sc + sh, 0.f);
          Cb[(long)(r0 + j) * Nn + cn] = f2b(v);
        }
      } else {
        const float bb = bias[cn];
        #pragma unroll
        for (int j = 0; j < 4; j++)
          Cf[(long)(r0 + j) * Nn + cn] = acc[m][n][j] + bb;
      }
    }
  }
#undef STG
#undef LDSA
#undef LDSB
#undef REGION_RD
#undef MF
#undef MHALF
#undef BARX
#undef LGK0
#undef PRIO1
#undef PRIO0
#undef VMC
#undef ITERBODY
}

extern "C" void kernel_launch(void* const* d_in, const int* in_sizes, int n_in,
                              void* d_out, int out_size, void* d_ws, size_t ws_size,
                              hipStream_t stream) {
  const float* X     = (const float*)d_in[0];
  const float* W_att = (const float*)d_in[1];
  const float* b_att = (const float*)d_in[2];
  const float* W1    = (const float*)d_in[3];
  // d_in[4] = b1: cancels exactly in BN (mean-subtracted) -> unused
  const float* gamma = (const float*)d_in[5];
  const float* beta  = (const float*)d_in[6];
  const float* W2    = (const float*)d_in[7];
  const float* b2    = (const float*)d_in[8];
  float* out = (float*)d_out;

  char* ws = (char*)d_ws;
  unsigned short* Wab = (unsigned short*)(ws + 0);            //  8 MB
  unsigned short* W1b = (unsigned short*)(ws + 8388608);      //  8 MB
  unsigned short* W2b = (unsigned short*)(ws + 16777216);     //  8 MB
  float*          PatA= (float*)        (ws + 25165824);      //  8 MB (split-K partials 0,1)
  unsigned short* Xg  = (unsigned short*)(ws + 33554432);     // 32 MB
  unsigned short* Hr  = (unsigned short*)(ws + 67108864);     // 32 MB
  // Aliases into the Hr region: both consumed strictly before Hr is written.
  unsigned short* Mb  = (unsigned short*)(ws + 67108864);     //  2 MB (alias)
  float*          PatB= (float*)        (ws + 67108864 + 2097152); // 8 MB (alias; partials 2,3)

  hipLaunchKernelGGL(cast3_kernel, dim3(12288), dim3(256), 0, stream,
                     W_att, W1, W2, Wab, W1b, W2b);
  hipLaunchKernelGGL(mean_cast_kernel, dim3(1024), dim3(256), 0, stream, X, Mb);
  hipLaunchKernelGGL(gemm_att_sk, dim3(4, 16, 4), dim3(256), 0, stream,
                     Mb, Wab, PatA, PatB);
  hipLaunchKernelGGL(gate_kernel, dim3(16384), dim3(256), 0, stream,
                     X, PatA, PatB, b_att, Xg);
  // grid = (M/256)*(N/256) = 32*8 = 256, %8==0 -> bijective XCD swizzle
  hipLaunchKernelGGL((gemm256<1>), dim3(256), dim3(512), 0, stream,
                     Xg, W1b, Cdim, Cdim, 32, nullptr, gamma, beta, nullptr, Hr);
  hipLaunchKernelGGL((gemm256<2>), dim3(256), dim3(512), 0, stream,
                     Hr, W2b, Cdim, Cdim, 32, b2, nullptr, nullptr, out, nullptr);
}

// Round 11
// 175.452 us; speedup vs baseline: 1.0743x; 1.0743x over previous
//
#include <hip/hip_runtime.h>
#include <hip/hip_bf16.h>

typedef __attribute__((ext_vector_type(8))) short short8;
typedef __attribute__((ext_vector_type(4))) float f32x4;

static constexpr int Cdim = 2048;
static constexpr int NFRM = 512;        // B*T
static constexpr int Pdim = 16;
static constexpr int MROWS = NFRM * Pdim;   // 8192
static constexpr float EPS = 1e-5f;

// round-to-nearest-even fp32 -> bf16 bits
__device__ __forceinline__ unsigned short f2b(float x) {
  union { float f; unsigned u; } v; v.f = x;
  unsigned r = v.u + 0x7fffu + ((v.u >> 16) & 1u);
  return (unsigned short)(r >> 16);
}

__device__ __forceinline__ float b2f(unsigned short b) {
  union { float f; unsigned u; } v; v.u = (unsigned)b << 16;
  return v.f;
}

__device__ __forceinline__ void gload16(const void* g, void* l) {
  __builtin_amdgcn_global_load_lds(
      (const __attribute__((address_space(1))) unsigned int*)g,
      (__attribute__((address_space(3))) unsigned int*)l, 16, 0, 0);
}

// ---------------- merged prep kernel: weight casts + per-frame mean ----------------
// blocks 0..12287: cast W_att/W1/W2 fp32->bf16 (float4 granularity)
// blocks 12288..13311: mean over P=16 rows per frame -> bf16 Mb[512,2048]
__global__ __launch_bounds__(256) void prep0_kernel(
    const float* __restrict__ s0, const float* __restrict__ s1, const float* __restrict__ s2,
    unsigned short* __restrict__ d0, unsigned short* __restrict__ d1, unsigned short* __restrict__ d2,
    const float* __restrict__ X, unsigned short* __restrict__ Mb)
{
  const int bid = blockIdx.x;
  if (bid < 12288) {
    long i = (long)bid * 256 + threadIdx.x;
    const float* s; unsigned short* d; long off;
    if (i < 1048576)      { s = s0; d = d0; off = i; }
    else if (i < 2097152) { s = s1; d = d1; off = i - 1048576; }
    else                  { s = s2; d = d2; off = i - 2097152; }
    float4 v = reinterpret_cast<const float4*>(s)[off];
    union { unsigned short u[4]; unsigned long long q; } o;
    o.u[0] = f2b(v.x); o.u[1] = f2b(v.y); o.u[2] = f2b(v.z); o.u[3] = f2b(v.w);
    *reinterpret_cast<unsigned long long*>(d + off * 4) = o.q;
  } else {
    int idx = (bid - 12288) * 256 + threadIdx.x;
    int n  = idx >> 9;
    int c4 = idx & 511;
    const float4* xp = reinterpret_cast<const float4*>(X) + (long)n * (Pdim * 512) + c4;
    float4 s = {0.f, 0.f, 0.f, 0.f};
    #pragma unroll
    for (int p = 0; p < Pdim; ++p) {
      float4 v = xp[(long)p * 512];
      s.x += v.x; s.y += v.y; s.z += v.z; s.w += v.w;
    }
    const float r = 1.f / 16.f;
    union { unsigned short u[4]; unsigned long long q; } o;
    o.u[0] = f2b(s.x * r); o.u[1] = f2b(s.y * r); o.u[2] = f2b(s.z * r); o.u[3] = f2b(s.w * r);
    *reinterpret_cast<unsigned long long*>(Mb + (long)idx * 4) = o.q;
  }
}

// attn partials (4-way split-K, bf16) -> sigmoid gate: a = sigmoid(sum P + b_att); Xg = bf16(X*a)
__global__ __launch_bounds__(256) void gate_kernel(
    const float* __restrict__ X, const unsigned short* __restrict__ PA,
    const unsigned short* __restrict__ PB,
    const float* __restrict__ b_att, unsigned short* __restrict__ Xg)
{
  constexpr long F = 512L * 2048;
  long idx = (long)blockIdx.x * 256 + threadIdx.x;
  int c4 = (int)(idx & 511);
  long np = idx >> 9;
  long n  = np >> 4;
  float4 x  = reinterpret_cast<const float4*>(X)[idx];
  ushort4 q0 = reinterpret_cast<const ushort4*>(PA)[n * 512 + c4];
  ushort4 q1 = reinterpret_cast<const ushort4*>(PA + F)[n * 512 + c4];
  ushort4 q2 = reinterpret_cast<const ushort4*>(PB)[n * 512 + c4];
  ushort4 q3 = reinterpret_cast<const ushort4*>(PB + F)[n * 512 + c4];
  float4 bb = reinterpret_cast<const float4*>(b_att)[c4];
  float4 a;
  a.x = 1.f / (1.f + __expf(-(b2f(q0.x) + b2f(q1.x) + b2f(q2.x) + b2f(q3.x) + bb.x)));
  a.y = 1.f / (1.f + __expf(-(b2f(q0.y) + b2f(q1.y) + b2f(q2.y) + b2f(q3.y) + bb.y)));
  a.z = 1.f / (1.f + __expf(-(b2f(q0.z) + b2f(q1.z) + b2f(q2.z) + b2f(q3.z) + bb.z)));
  a.w = 1.f / (1.f + __expf(-(b2f(q0.w) + b2f(q1.w) + b2f(q2.w) + b2f(q3.w) + bb.w)));
  union { unsigned short u[4]; unsigned long long q; } o;
  o.u[0] = f2b(x.x * a.x); o.u[1] = f2b(x.y * a.y);
  o.u[2] = f2b(x.z * a.z); o.u[3] = f2b(x.w * a.w);
  *reinterpret_cast<unsigned long long*>(Xg + idx * 4) = o.q;
}

// ---------------- small attn GEMM, split-K=4, bf16 partial outputs ----------------
__global__ __launch_bounds__(256) void gemm_att_sk(
    const unsigned short* __restrict__ A,
    const unsigned short* __restrict__ B,
    unsigned short* __restrict__ PA, unsigned short* __restrict__ PB)
{
  constexpr int N = 2048, K = 2048, KH = 512;
  constexpr long F = 512L * 2048;
  __shared__ unsigned short As[128 * 32];
  __shared__ unsigned short Bs[128 * 32];
  const int t = threadIdx.x;
  const int lane = t & 63;
  const int wid = t >> 6;
  const int wr = wid >> 1, wc = wid & 1;
  const int m0 = blockIdx.x * 128, n0 = blockIdx.y * 128;
  const int k0 = blockIdx.z * KH;
  unsigned short* out = (blockIdx.z < 2) ? (PA + (long)blockIdx.z * F) : (PB + (long)(blockIdx.z - 2) * F);

  f32x4 acc[4][4];
  #pragma unroll
  for (int i = 0; i < 4; i++)
    #pragma unroll
    for (int j = 0; j < 4; j++) acc[i][j] = (f32x4){0.f, 0.f, 0.f, 0.f};

  const int srow = t >> 2;
  const int scol = (t & 3) * 8;
  const long aoff0 = (long)(m0 + srow) * K + scol;
  const long aoff1 = (long)(m0 + 64 + srow) * K + scol;
  const long boff0 = (long)(n0 + srow) * K + scol;
  const long boff1 = (long)(n0 + 64 + srow) * K + scol;
  char* AsB = (char*)As;
  char* BsB = (char*)Bs;

  const int fr = lane & 15;
  const int fk = (lane >> 4) * 8;

  for (int kt = k0; kt < k0 + KH; kt += 32) {
    __syncthreads();
    gload16(A + aoff0 + kt, AsB + t * 16);
    gload16(A + aoff1 + kt, AsB + 4096 + t * 16);
    gload16(B + boff0 + kt, BsB + t * 16);
    gload16(B + boff1 + kt, BsB + 4096 + t * 16);
    __syncthreads();
    short8 af[4], bfr[4];
    #pragma unroll
    for (int m = 0; m < 4; m++)
      af[m] = *reinterpret_cast<const short8*>(&As[(wr * 64 + m * 16 + fr) * 32 + fk]);
    #pragma unroll
    for (int n = 0; n < 4; n++)
      bfr[n] = *reinterpret_cast<const short8*>(&Bs[(wc * 64 + n * 16 + fr) * 32 + fk]);
    #pragma unroll
    for (int m = 0; m < 4; m++)
      #pragma unroll
      for (int n = 0; n < 4; n++)
        acc[m][n] = __builtin_amdgcn_mfma_f32_16x16x32_bf16(af[m], bfr[n], acc[m][n], 0, 0, 0);
  }

  const int l4 = lane >> 4;
  #pragma unroll
  for (int m = 0; m < 4; m++) {
    const int r0 = m0 + wr * 64 + m * 16 + l4 * 4;
    #pragma unroll
    for (int n = 0; n < 4; n++) {
      const int cn = n0 + wc * 64 + n * 16 + fr;
      #pragma unroll
      for (int j = 0; j < 4; j++)
        out[(long)(r0 + j) * N + cn] = f2b(acc[m][n][j]);
    }
  }
}

// --- 256^2 single-barrier 8-phase GEMM, 16x16x32 (R8 skeleton, deeper vmcnt slack) ---
// C[M,N] = A[M,K] @ B[N,K]^T, bf16 in / fp32 acc.
//   EPI=1: Cb = bf16(relu(BN_P16(acc)*gamma+beta))
//   EPI=2: Cf = acc + bias
// R11 change vs R8: BOTH A-halves staged at P1 (A(o)) and P5 (A(e+2)).
// WAR audit: buf1-A last read P7(i-1) (retired pre-QUAD7, fence BARX8) -> P1 ok;
// buf0-A last read P3 (fence BARX4) -> P5 ok. vmcnt sites unchanged
// {P3:4, P4:2, P7:4, P8:2} but binding waits now have 3-phase slack
// (P4 waits P1's stage; P8 waits P5's) instead of 2 -> covers HBM latency.
// Outstanding trace: carry4 ->P1:8 ->P2:8 ->P3:VMC4,+2=6 ->P4:VMC2,+2=4
// ->P5:8 ->P6:8 ->P7:VMC4,+2=6 ->P8:VMC2,+2=4 = carry ✓.
template<int EPI>
__global__ __launch_bounds__(512, 2) void gemm256(
    const unsigned short* __restrict__ A,
    const unsigned short* __restrict__ Bp,
    int Kk, int Nn, int nbx,
    const float* __restrict__ bias,
    const float* __restrict__ gamma,
    const float* __restrict__ beta,
    float* __restrict__ Cf,
    unsigned short* __restrict__ Cb)
{
  __shared__ char lds[131072];
  const int t = threadIdx.x;
  const int lane = t & 63;
  const int wid = t >> 6;
  const int wr = wid >> 2;        // 0..1  (M-half)
  const int wc = wid & 3;         // 0..3  (N-quarter)

  // T1: bijective XCD swizzle (gridDim.x % 8 == 0 by construction)
  const int nw = gridDim.x;
  const int wg = (blockIdx.x & 7) * (nw >> 3) + (blockIdx.x >> 3);
  const int bx = wg % nbx;
  const int by = wg / nbx;
  const int m0 = bx << 8, n0 = by << 8;

  const int NT = Kk >> 6;         // K-tiles (BK=64), even, >=4
  const int NI = NT >> 1;         // unroll-2 iterations

  const long h64 = (long)64 * Kk, h128 = (long)128 * Kk;
  const int row0 = t >> 3;
  const int col0 = ((t & 7) * 8) ^ ((row0 & 7) << 3);   // pre-swizzled source col (elems)
  const unsigned short* gA = A  + (long)(m0 + row0) * Kk + col0;
  const unsigned short* gB = Bp + (long)(n0 + row0) * Kk + col0;

  const int fr_ = lane & 15;
  const int cb0 = ((lane >> 4) << 4) ^ ((fr_ & 7) << 4); // swizzled read col (bytes)
  const int aB = (wr << 14) + fr_ * 128;
  const int bB = 32768 + ((wc >> 1) << 14) + ((wc & 1) << 13) + fr_ * 128;

#define STG(gp_, ko_, lo_) do { \
    const unsigned short* g0_ = (gp_) + (ko_); \
    gload16(g0_, lds + (lo_) + (t << 4)); \
    gload16(g0_ + h64, lds + (lo_) + 8192 + (t << 4)); } while (0)

#define LDSA(buf_, m_, ks_) (*(const short8*)(lds + (buf_) * 65536 + aB + (m_) * 2048 + (cb0 ^ ((ks_) << 6))))
#define LDSB(buf_, n_, ks_) (*(const short8*)(lds + (buf_) * 65536 + bB + (n_) * 2048 + (cb0 ^ ((ks_) << 6))))

#define RDAF(buf_, mb_) do { \
    af[0][0] = LDSA(buf_, (mb_) + 0, 0); af[0][1] = LDSA(buf_, (mb_) + 0, 1); \
    af[1][0] = LDSA(buf_, (mb_) + 1, 0); af[1][1] = LDSA(buf_, (mb_) + 1, 1); \
    af[2][0] = LDSA(buf_, (mb_) + 2, 0); af[2][1] = LDSA(buf_, (mb_) + 2, 1); \
    af[3][0] = LDSA(buf_, (mb_) + 3, 0); af[3][1] = LDSA(buf_, (mb_) + 3, 1); } while (0)

#define RDB(buf_, nb_, dst_) do { \
    dst_[0][0] = LDSB(buf_, (nb_) + 0, 0); dst_[0][1] = LDSB(buf_, (nb_) + 0, 1); \
    dst_[1][0] = LDSB(buf_, (nb_) + 1, 0); dst_[1][1] = LDSB(buf_, (nb_) + 1, 1); } while (0)

#define QUAD(mb_, nb_, b_) do { \
    _Pragma("unroll") \
    for (int mi = 0; mi < 4; ++mi) { \
      _Pragma("unroll") \
      for (int ni = 0; ni < 2; ++ni) { \
        acc[(mb_) + mi][(nb_) + ni] = __builtin_amdgcn_mfma_f32_16x16x32_bf16(af[mi][0], b_[ni][0], acc[(mb_) + mi][(nb_) + ni], 0, 0, 0); \
        acc[(mb_) + mi][(nb_) + ni] = __builtin_amdgcn_mfma_f32_16x16x32_bf16(af[mi][1], b_[ni][1], acc[(mb_) + mi][(nb_) + ni], 0, 0, 0); \
      } } } while (0)

#define BARX() do { \
    __builtin_amdgcn_sched_barrier(0); \
    __builtin_amdgcn_s_barrier(); \
    __builtin_amdgcn_sched_barrier(0); } while (0)

#define PRIO1() __builtin_amdgcn_s_setprio(1)
#define PRIO0() __builtin_amdgcn_s_setprio(0)
#define VMC(n_) asm volatile("s_waitcnt vmcnt(" #n_ ")" ::: "memory")

  f32x4 acc[8][4];
  #pragma unroll
  for (int i = 0; i < 8; i++)
    #pragma unroll
    for (int j = 0; j < 4; j++) acc[i][j] = (f32x4){0.f, 0.f, 0.f, 0.f};

  short8 af[4][2], b23[2][2], bE0[2][2], bO0[2][2];

  // prologue: A0(0),A1(0),B0(0),B1(0),B0(1),B1(1); confirm first 4; pre-read bE0(0).
  STG(gA, 0, 0);
  STG(gA + h128, 0, 16384);
  STG(gB, 0, 32768);
  STG(gB + h128, 0, 49152);
  STG(gB, 64, 98304);
  STG(gB + h128, 64, 114688);
  VMC(4);
  __builtin_amdgcn_s_barrier();
  __builtin_amdgcn_sched_barrier(0);
  RDB(0, 0, bE0);

#define ITERBODY(LAST_) do { \
    /* P1: q00(e); stage BOTH A halves (o) */ \
    STG(gA, ko + 64, 65536); \
    STG(gA + h128, ko + 64, 81920); \
    RDAF(0, 0); \
    BARX(); PRIO1(); QUAD(0, 0, bE0); PRIO0(); \
    /* P2: q01(e); no stage */ \
    RDB(0, 2, b23); \
    BARX(); PRIO1(); QUAD(0, 2, b23); PRIO0(); \
    /* P3: q10(e); vmcnt confirms B(o); stage B0(e+2) */ \
    VMC(4); \
    if (!(LAST_)) STG(gB, ko + 128, 32768); \
    RDAF(0, 4); \
    BARX(); PRIO1(); QUAD(4, 0, bE0); PRIO0(); \
    /* P4: q11(e); vmcnt confirms A(o) (3-phase slack); stage B1(e+2); pre-read b0(o) */ \
    if (LAST_) { VMC(0); } else { VMC(2); STG(gB + h128, ko + 128, 49152); } \
    RDB(1, 0, bO0); \
    BARX(); PRIO1(); QUAD(4, 2, b23); PRIO0(); \
    /* P5: q00(o); stage BOTH A halves (e+2) */ \
    if (!(LAST_)) { STG(gA, ko + 128, 0); STG(gA + h128, ko + 128, 16384); } \
    RDAF(1, 0); \
    BARX(); PRIO1(); QUAD(0, 0, bO0); PRIO0(); \
    /* P6: q01(o); no stage */ \
    RDB(1, 2, b23); \
    BARX(); PRIO1(); QUAD(0, 2, b23); PRIO0(); \
    /* P7: q10(o); vmcnt confirms B(e+2); stage B0(o+2) */ \
    if (!(LAST_)) { VMC(4); STG(gB, ko + 192, 98304); } \
    RDAF(1, 4); \
    BARX(); PRIO1(); QUAD(4, 0, bO0); PRIO0(); \
    /* P8: q11(o); vmcnt confirms A(e+2) (3-phase slack); stage B1(o+2); pre-read bE0' */ \
    if (!(LAST_)) { VMC(2); STG(gB + h128, ko + 192, 114688); RDB(0, 0, bE0); } \
    BARX(); PRIO1(); QUAD(4, 2, b23); PRIO0(); \
  } while (0)

  long ko = 0;
  for (int i = 0; i < NI - 1; ++i, ko += 128) {
    ITERBODY(0);
  }
  ITERBODY(1);

  // ---- epilogue (acc only; no LDS use, no barrier needed)
  const int l4 = lane >> 4;
  #pragma unroll
  for (int m = 0; m < 8; ++m) {
    const int r0 = m0 + wr * 128 + m * 16 + l4 * 4;
    #pragma unroll
    for (int n = 0; n < 4; ++n) {
      const int cn = n0 + wc * 64 + n * 16 + fr_;
      if constexpr (EPI == 1) {
        float s1 = 0.f, s2 = 0.f;
        #pragma unroll
        for (int j = 0; j < 4; j++) { float v = acc[m][n][j]; s1 += v; s2 += v * v; }
        s1 += __shfl_xor(s1, 16); s2 += __shfl_xor(s2, 16);
        s1 += __shfl_xor(s1, 32); s2 += __shfl_xor(s2, 32);
        const float mean = s1 * 0.0625f;
        const float var  = s2 * 0.0625f - mean * mean;
        const float sc = rsqrtf(var + EPS) * gamma[cn];
        const float sh = beta[cn] - mean * sc;
        #pragma unroll
        for (int j = 0; j < 4; j++) {
          float v = fmaxf(acc[m][n][j] * sc + sh, 0.f);
          Cb[(long)(r0 + j) * Nn + cn] = f2b(v);
        }
      } else {
        const float bb = bias[cn];
        #pragma unroll
        for (int j = 0; j < 4; j++)
          Cf[(long)(r0 + j) * Nn + cn] = acc[m][n][j] + bb;
      }
    }
  }
#undef STG
#undef LDSA
#undef LDSB
#undef RDAF
#undef RDB
#undef QUAD
#undef BARX
#undef PRIO1
#undef PRIO0
#undef VMC
#undef ITERBODY
}

extern "C" void kernel_launch(void* const* d_in, const int* in_sizes, int n_in,
                              void* d_out, int out_size, void* d_ws, size_t ws_size,
                              hipStream_t stream) {
  const float* X     = (const float*)d_in[0];
  const float* W_att = (const float*)d_in[1];
  const float* b_att = (const float*)d_in[2];
  const float* W1    = (const float*)d_in[3];
  // d_in[4] = b1: cancels exactly in BN (mean-subtracted) -> unused
  const float* gamma = (const float*)d_in[5];
  const float* beta  = (const float*)d_in[6];
  const float* W2    = (const float*)d_in[7];
  const float* b2    = (const float*)d_in[8];
  float* out = (float*)d_out;

  char* ws = (char*)d_ws;
  unsigned short* Wab = (unsigned short*)(ws + 0);            //  8 MB
  unsigned short* W1b = (unsigned short*)(ws + 8388608);      //  8 MB
  unsigned short* W2b = (unsigned short*)(ws + 16777216);     //  8 MB
  unsigned short* PatA= (unsigned short*)(ws + 25165824);     //  4 MB (bf16 split-K partials 0,1)
  unsigned short* Xg  = (unsigned short*)(ws + 33554432);     // 32 MB
  unsigned short* Hr  = (unsigned short*)(ws + 67108864);     // 32 MB
  // Aliases into the Hr region: both consumed strictly before Hr is written.
  unsigned short* Mb  = (unsigned short*)(ws + 67108864);     //  2 MB (alias)
  unsigned short* PatB= (unsigned short*)(ws + 67108864 + 2097152); // 4 MB (alias; partials 2,3)

  hipLaunchKernelGGL(prep0_kernel, dim3(13312), dim3(256), 0, stream,
                     W_att, W1, W2, Wab, W1b, W2b, X, Mb);
  hipLaunchKernelGGL(gemm_att_sk, dim3(4, 16, 4), dim3(256), 0, stream,
                     Mb, Wab, PatA, PatB);
  hipLaunchKernelGGL(gate_kernel, dim3(16384), dim3(256), 0, stream,
                     X, PatA, PatB, b_att, Xg);
  // grid = (M/256)*(N/256) = 32*8 = 256, %8==0 -> bijective XCD swizzle
  hipLaunchKernelGGL((gemm256<1>), dim3(256), dim3(512), 0, stream,
                     Xg, W1b, Cdim, Cdim, 32, nullptr, gamma, beta, nullptr, Hr);
  hipLaunchKernelGGL((gemm256<2>), dim3(256), dim3(512), 0, stream,
                     Hr, W2b, Cdim, Cdim, 32, b2, nullptr, nullptr, out, nullptr);
}